// Round 1
// baseline (521.058 us; speedup 1.0000x reference)
//
#include <hip/hip_runtime.h>

// Problem constants (from setup_inputs): N=256, C=3, T=300, V=25, M=2, D=256,
// K=5 classes, topk=64, NMT = 153600 rows of x_T.
#define NROWS   153600
#define D       256
#define NCLS    5
#define NSAMP   256
#define TT      300
#define TOPK    64
#define VM      50        // V*M inner contiguous span of x
#define EPSF    1e-8f

// ---- workspace layout (floats) ----
// [0,1280)      class sums [5][256]
// [1280,1285)   counts [5]
// 1285          Sw
// 1286          Sb
// [1288,2568)   class_mean [5][256]
// [2568,2573)   inter [5]
// [2576,156176) frame_scores [153600]
#define WS_SUMS   0
#define WS_CNT    1280
#define WS_SW     1285
#define WS_SB     1286
#define WS_CMEAN  1288
#define WS_INTER  2568
#define WS_FS     2576
#define WS_ZERO_N 1288   // floats to zero (sums+counts+Sw+Sb)

__global__ __launch_bounds__(256) void zero_kernel(float* __restrict__ ws) {
    int i = blockIdx.x * 256 + threadIdx.x;
    if (i < WS_ZERO_N) ws[i] = 0.0f;
}

// 600 blocks x 256 threads; 256 rows/block; 4 row-groups of 64 lanes, float4 per lane.
__global__ __launch_bounds__(256) void class_sums_kernel(const float4* __restrict__ xT4,
                                                         const int* __restrict__ labels,
                                                         float* __restrict__ sums,
                                                         float* __restrict__ counts) {
    __shared__ float buf[4][NCLS][D];
    const int tid  = threadIdx.x;
    const int sub  = tid >> 6;     // which row of the 4 concurrent rows
    const int lane = tid & 63;
    const int r0   = blockIdx.x * 256;

    float acc[NCLS][4];
    #pragma unroll
    for (int c = 0; c < NCLS; ++c)
        #pragma unroll
        for (int k = 0; k < 4; ++k) acc[c][k] = 0.0f;
    float cnt[NCLS] = {0.f, 0.f, 0.f, 0.f, 0.f};

    #pragma unroll 2
    for (int j = 0; j < 64; ++j) {
        const int r = r0 + j * 4 + sub;
        const int l = labels[r];
        const float4 v = xT4[(size_t)r * (D / 4) + lane];
        #pragma unroll
        for (int c = 0; c < NCLS; ++c) {
            const bool m = (l == c);
            acc[c][0] += m ? v.x : 0.0f;
            acc[c][1] += m ? v.y : 0.0f;
            acc[c][2] += m ? v.z : 0.0f;
            acc[c][3] += m ? v.w : 0.0f;
            if (lane == 0) cnt[c] += m ? 1.0f : 0.0f;
        }
    }

    #pragma unroll
    for (int c = 0; c < NCLS; ++c)
        #pragma unroll
        for (int k = 0; k < 4; ++k)
            buf[sub][c][lane * 4 + k] = acc[c][k];
    __syncthreads();

    #pragma unroll
    for (int c = 0; c < NCLS; ++c) {
        const float s = buf[0][c][tid] + buf[1][c][tid] + buf[2][c][tid] + buf[3][c][tid];
        atomicAdd(&sums[c * D + tid], s);
    }
    if (lane == 0) {
        #pragma unroll
        for (int c = 0; c < NCLS; ++c) atomicAdd(&counts[c], cnt[c]);
    }
}

// single block, 256 threads (thread = dim d)
__global__ __launch_bounds__(256) void finalize_kernel(const float* __restrict__ sums,
                                                       const float* __restrict__ counts,
                                                       float* __restrict__ cmean,
                                                       float* __restrict__ inter,
                                                       float* __restrict__ sb) {
    __shared__ float red[256];
    const int d = threadIdx.x;
    float s[NCLS];
    float osum = 0.0f;
    #pragma unroll
    for (int c = 0; c < NCLS; ++c) { s[c] = sums[c * D + d]; osum += s[c]; }
    const float om = osum / (float)NROWS;

    float sbacc = 0.0f;
    #pragma unroll
    for (int c = 0; c < NCLS; ++c) {
        const float cnt = counts[c];
        const float mm  = s[c] / fmaxf(cnt, 1.0f);
        cmean[c * D + d] = mm;
        const float diff = mm - om;
        red[d] = diff * diff;
        __syncthreads();
        for (int off = 128; off > 0; off >>= 1) {
            if (d < off) red[d] += red[d + off];
            __syncthreads();
        }
        if (d == 0) { inter[c] = red[0]; sbacc += cnt * red[0]; }
        __syncthreads();
    }
    if (d == 0) sb[0] = sbacc;
}

// one wave per row: 64 lanes x float4 = 1 KB row
__global__ __launch_bounds__(256) void intra_kernel(const float4* __restrict__ xT4,
                                                    const int* __restrict__ labels,
                                                    const float4* __restrict__ cmean4,
                                                    const float* __restrict__ inter,
                                                    float* __restrict__ fs,
                                                    float* __restrict__ Sw) {
    const int lane   = threadIdx.x & 63;
    const int wave   = (blockIdx.x * blockDim.x + threadIdx.x) >> 6;
    const int nwaves = (gridDim.x * blockDim.x) >> 6;
    float swacc = 0.0f;
    for (int r = wave; r < NROWS; r += nwaves) {
        const int l = labels[r];
        const float4 xv = xT4[(size_t)r * (D / 4) + lane];
        const float4 mv = cmean4[l * (D / 4) + lane];
        const float dx = xv.x - mv.x, dy = xv.y - mv.y;
        const float dz = xv.z - mv.z, dw = xv.w - mv.w;
        float sacc = dx * dx + dy * dy + dz * dz + dw * dw;
        #pragma unroll
        for (int o = 32; o > 0; o >>= 1) sacc += __shfl_xor(sacc, o, 64);
        if (lane == 0) {
            fs[r] = inter[l] / (sacc + EPSF);
            swacc += sacc;
        }
    }
    if (lane == 0) atomicAdd(Sw, swacc);
}

// 256 blocks (one per sample n), 256 threads
__global__ __launch_bounds__(256) void topk_gather_kernel(const float* __restrict__ fs,
                                                          const float* __restrict__ x,
                                                          const float* __restrict__ swsb,
                                                          float* __restrict__ out) {
    __shared__ float VF[TT];
    __shared__ int   rnk[TT];
    __shared__ int   idxL[TOPK];
    const int n   = blockIdx.x;
    const int tid = threadIdx.x;

    if (n == 0 && tid == 0) out[0] = swsb[0] / (swsb[1] + EPSF);

    const float* f0 = fs + (size_t)n * (2 * TT);
    for (int t = tid; t < TT; t += 256) VF[t] = 0.5f * (f0[t] + f0[t + TT]);
    __syncthreads();

    // rank = #{u : VF[u] > VF[t]  or (VF[u]==VF[t] and u<t)}  -> matches top_k tie-break
    for (int t = tid; t < TT; t += 256) {
        const float v = VF[t];
        int r = 0;
        for (int u = 0; u < TT; ++u) {
            const float w = VF[u];
            r += (w > v) || (w == v && u < t);
        }
        rnk[t] = r;
    }
    __syncthreads();

    // stable compaction of selected indices -> ascending order (== sort(idx))
    for (int t = tid; t < TT; t += 256) {
        if (rnk[t] < TOPK) {
            int pos = 0;
            for (int u = 0; u < t; ++u) pos += (rnk[u] < TOPK);
            idxL[pos] = t;
        }
    }
    __syncthreads();

    // gather x[n, c, idx[j], v, m] -> out[1 + n*C*TOPK*VM ...]
    const float* xb = x + (size_t)n * 3 * TT * VM;
    float* ob = out + 1 + (size_t)n * 3 * TOPK * VM;
    for (int o = tid; o < 3 * TOPK * VM; o += 256) {
        const int c   = o / (TOPK * VM);
        const int rem = o - c * (TOPK * VM);
        const int j   = rem / VM;
        const int s   = rem - j * VM;
        const int t   = idxL[j];
        ob[(c * TOPK + j) * VM + s] = xb[(c * TT + t) * VM + s];
    }
}

extern "C" void kernel_launch(void* const* d_in, const int* in_sizes, int n_in,
                              void* d_out, int out_size, void* d_ws, size_t ws_size,
                              hipStream_t stream) {
    const float* x      = (const float*)d_in[0];
    const float* xT     = (const float*)d_in[1];
    const int*   labels = (const int*)d_in[2];
    float* out = (float*)d_out;
    float* ws  = (float*)d_ws;

    float* sums   = ws + WS_SUMS;
    float* counts = ws + WS_CNT;
    float* Sw     = ws + WS_SW;
    float* Sb     = ws + WS_SB;
    float* cmean  = ws + WS_CMEAN;
    float* inter  = ws + WS_INTER;
    float* fs     = ws + WS_FS;

    hipLaunchKernelGGL(zero_kernel, dim3((WS_ZERO_N + 255) / 256), dim3(256), 0, stream, ws);
    hipLaunchKernelGGL(class_sums_kernel, dim3(NROWS / 256), dim3(256), 0, stream,
                       (const float4*)xT, labels, sums, counts);
    hipLaunchKernelGGL(finalize_kernel, dim3(1), dim3(256), 0, stream,
                       sums, counts, cmean, inter, Sb);
    hipLaunchKernelGGL(intra_kernel, dim3(640), dim3(256), 0, stream,
                       (const float4*)xT, labels, (const float4*)cmean, inter, fs, Sw);
    hipLaunchKernelGGL(topk_gather_kernel, dim3(NSAMP), dim3(256), 0, stream,
                       fs, x, ws + WS_SW, out);
}

// Round 2
// 327.635 us; speedup vs baseline: 1.5904x; 1.5904x over previous
//
#include <hip/hip_runtime.h>

// Problem constants: N=256, C=3, T=300, V=25, M=2, D=256, K=5, topk=64.
#define NROWS   153600
#define D       256
#define D4      64        // D/4 float4s per row
#define NCLS    5
#define NSAMP   256
#define TT      300
#define TOPK    64
#define VM      50        // V*M inner contiguous span of x
#define EPSF    1e-8f

// ---- workspace layout (floats) ----
#define WS_SUMS   0        // [5][256] class sums
#define WS_CNT    1280     // [5] counts
#define WS_SQ     1285     // total sum of squares
#define WS_ZERO_N 1288
#define WS_CMEAN  1288     // [5][256]
#define WS_INTER  2568     // [5]
#define WS_FS     2576     // [153600] frame scores

__global__ __launch_bounds__(256) void zero_kernel(float* __restrict__ ws) {
    int i = blockIdx.x * 256 + threadIdx.x;
    if (i < WS_ZERO_N) ws[i] = 0.0f;
}

// 1200 blocks x 256 threads. 128 rows/block; 4 waves, 32 rows/wave, batch 8.
__global__ __launch_bounds__(256) void class_sums_kernel(const float4* __restrict__ xT4,
                                                         const int* __restrict__ labels,
                                                         float* __restrict__ sums,
                                                         float* __restrict__ counts,
                                                         float* __restrict__ sumsq) {
    __shared__ float buf[4][NCLS][D];
    __shared__ float sbuf[4][8];
    const int tid  = threadIdx.x;
    const int sub  = tid >> 6;
    const int lane = tid & 63;
    const int r0   = blockIdx.x * 128 + sub * 32;

    float acc[NCLS][4];
    #pragma unroll
    for (int c = 0; c < NCLS; ++c)
        #pragma unroll
        for (int k = 0; k < 4; ++k) acc[c][k] = 0.0f;
    float cnt[NCLS] = {0.f, 0.f, 0.f, 0.f, 0.f};
    float sq = 0.0f;

    #pragma unroll 1
    for (int jb = 0; jb < 32; jb += 8) {
        int l[8]; float4 v[8];
        #pragma unroll
        for (int k = 0; k < 8; ++k) {
            const int r = r0 + jb + k;
            l[k] = labels[r];
            v[k] = xT4[(size_t)r * D4 + lane];
        }
        #pragma unroll
        for (int k = 0; k < 8; ++k) {
            sq += v[k].x * v[k].x + v[k].y * v[k].y + v[k].z * v[k].z + v[k].w * v[k].w;
            #pragma unroll
            for (int c = 0; c < NCLS; ++c) {
                const bool m = (l[k] == c);
                acc[c][0] += m ? v[k].x : 0.0f;
                acc[c][1] += m ? v[k].y : 0.0f;
                acc[c][2] += m ? v[k].z : 0.0f;
                acc[c][3] += m ? v[k].w : 0.0f;
                cnt[c]    += m ? 1.0f : 0.0f;   // wave-uniform
            }
        }
    }

    // lane-reduce sq (cnt is wave-uniform already)
    #pragma unroll
    for (int o = 32; o > 0; o >>= 1) sq += __shfl_xor(sq, o, 64);

    #pragma unroll
    for (int c = 0; c < NCLS; ++c)
        *(float4*)&buf[sub][c][lane * 4] =
            make_float4(acc[c][0], acc[c][1], acc[c][2], acc[c][3]);
    if (lane == 0) {
        #pragma unroll
        for (int c = 0; c < NCLS; ++c) sbuf[sub][c] = cnt[c];
        sbuf[sub][5] = sq;
    }
    __syncthreads();

    #pragma unroll
    for (int c = 0; c < NCLS; ++c) {
        const float s = buf[0][c][tid] + buf[1][c][tid] + buf[2][c][tid] + buf[3][c][tid];
        atomicAdd(&sums[c * D + tid], s);
    }
    if (tid < 6) {
        const float s = sbuf[0][tid] + sbuf[1][tid] + sbuf[2][tid] + sbuf[3][tid];
        if (tid < 5) atomicAdd(&counts[tid], s);
        else         atomicAdd(sumsq, s);
    }
}

// single block, 256 threads (thread = dim d). Also computes loss -> out[0].
__global__ __launch_bounds__(256) void finalize_kernel(const float* __restrict__ sums,
                                                       const float* __restrict__ counts,
                                                       const float* __restrict__ sumsq,
                                                       float* __restrict__ cmean,
                                                       float* __restrict__ inter,
                                                       float* __restrict__ out) {
    __shared__ float r1[256], r2[256];
    const int d = threadIdx.x;
    float s[NCLS];
    float osum = 0.0f;
    #pragma unroll
    for (int c = 0; c < NCLS; ++c) { s[c] = sums[c * D + d]; osum += s[c]; }
    const float om = osum / (float)NROWS;

    float sb = 0.0f, swn = 0.0f;
    #pragma unroll
    for (int c = 0; c < NCLS; ++c) {
        const float cnt = counts[c];
        const float mm  = s[c] / fmaxf(cnt, 1.0f);
        cmean[c * D + d] = mm;
        const float diff = mm - om;
        r1[d] = diff * diff;
        r2[d] = mm * mm;
        __syncthreads();
        for (int off = 128; off > 0; off >>= 1) {
            if (d < off) { r1[d] += r1[d + off]; r2[d] += r2[d + off]; }
            __syncthreads();
        }
        if (d == 0) {
            inter[c] = r1[0];
            sb  += cnt * r1[0];
            swn += cnt * r2[0];
        }
        __syncthreads();
    }
    if (d == 0) {
        const float Sw = sumsq[0] - swn;   // exact identity for Sum of intra
        out[0] = Sw / (sb + EPSF);
    }
}

// 1200 blocks x 256 threads; wave-per-row, 32 rows/wave, batch 8; means in LDS.
__global__ __launch_bounds__(256) void intra_kernel(const float4* __restrict__ xT4,
                                                    const int* __restrict__ labels,
                                                    const float4* __restrict__ cmean4,
                                                    const float* __restrict__ inter,
                                                    float* __restrict__ fs) {
    __shared__ float cm[NCLS * D];
    __shared__ float sinter[NCLS];
    const int tid  = threadIdx.x;
    const int sub  = tid >> 6;
    const int lane = tid & 63;

    for (int i = tid; i < NCLS * D4; i += 256)
        ((float4*)cm)[i] = cmean4[i];
    if (tid < NCLS) sinter[tid] = inter[tid];
    __syncthreads();

    const int r0 = blockIdx.x * 128 + sub * 32;
    #pragma unroll 1
    for (int jb = 0; jb < 32; jb += 8) {
        int l[8]; float4 xv[8];
        #pragma unroll
        for (int k = 0; k < 8; ++k) {
            const int r = r0 + jb + k;
            l[k]  = labels[r];
            xv[k] = xT4[(size_t)r * D4 + lane];
        }
        float p[8];
        #pragma unroll
        for (int k = 0; k < 8; ++k) {
            const float4 mv = *(const float4*)&cm[l[k] * D + lane * 4];
            const float dx = xv[k].x - mv.x, dy = xv[k].y - mv.y;
            const float dz = xv[k].z - mv.z, dw = xv[k].w - mv.w;
            p[k] = dx * dx + dy * dy + dz * dz + dw * dw;
        }
        #pragma unroll
        for (int o = 32; o > 0; o >>= 1)
            #pragma unroll
            for (int k = 0; k < 8; ++k)
                p[k] += __shfl_xor(p[k], o, 64);
        if (lane == 0) {
            #pragma unroll
            for (int k = 0; k < 8; ++k)
                fs[r0 + jb + k] = sinter[l[k]] / (p[k] + EPSF);
        }
    }
}

// 256 blocks (one per sample), 256 threads
__global__ __launch_bounds__(256) void topk_gather_kernel(const float* __restrict__ fs,
                                                          const float* __restrict__ x,
                                                          float* __restrict__ out) {
    __shared__ float VF[TT];
    __shared__ int   rnk[TT];
    __shared__ int   idxL[TOPK];
    const int n   = blockIdx.x;
    const int tid = threadIdx.x;

    const float* f0 = fs + (size_t)n * (2 * TT);
    for (int t = tid; t < TT; t += 256) VF[t] = 0.5f * (f0[t] + f0[t + TT]);
    __syncthreads();

    // rank = #{u : VF[u] > VF[t] or (VF[u]==VF[t] and u<t)} -> top_k tie-break
    for (int t = tid; t < TT; t += 256) {
        const float v = VF[t];
        int r = 0;
        for (int u = 0; u < TT; ++u) {
            const float w = VF[u];
            r += (w > v) || (w == v && u < t);
        }
        rnk[t] = r;
    }
    __syncthreads();

    // stable compaction of selected indices -> ascending (== sort(idx))
    for (int t = tid; t < TT; t += 256) {
        if (rnk[t] < TOPK) {
            int pos = 0;
            for (int u = 0; u < t; ++u) pos += (rnk[u] < TOPK);
            idxL[pos] = t;
        }
    }
    __syncthreads();

    const float* xb = x + (size_t)n * 3 * TT * VM;
    float* ob = out + 1 + (size_t)n * 3 * TOPK * VM;
    for (int o = tid; o < 3 * TOPK * VM; o += 256) {
        const int c   = o / (TOPK * VM);
        const int rem = o - c * (TOPK * VM);
        const int j   = rem / VM;
        const int s   = rem - j * VM;
        const int t   = idxL[j];
        ob[(c * TOPK + j) * VM + s] = xb[(c * TT + t) * VM + s];
    }
}

extern "C" void kernel_launch(void* const* d_in, const int* in_sizes, int n_in,
                              void* d_out, int out_size, void* d_ws, size_t ws_size,
                              hipStream_t stream) {
    const float* x      = (const float*)d_in[0];
    const float* xT     = (const float*)d_in[1];
    const int*   labels = (const int*)d_in[2];
    float* out = (float*)d_out;
    float* ws  = (float*)d_ws;

    float* sums   = ws + WS_SUMS;
    float* counts = ws + WS_CNT;
    float* sumsq  = ws + WS_SQ;
    float* cmean  = ws + WS_CMEAN;
    float* inter  = ws + WS_INTER;
    float* fs     = ws + WS_FS;

    hipLaunchKernelGGL(zero_kernel, dim3((WS_ZERO_N + 255) / 256), dim3(256), 0, stream, ws);
    hipLaunchKernelGGL(class_sums_kernel, dim3(NROWS / 128), dim3(256), 0, stream,
                       (const float4*)xT, labels, sums, counts, sumsq);
    hipLaunchKernelGGL(finalize_kernel, dim3(1), dim3(256), 0, stream,
                       sums, counts, sumsq, cmean, inter, out);
    hipLaunchKernelGGL(intra_kernel, dim3(NROWS / 128), dim3(256), 0, stream,
                       (const float4*)xT, labels, (const float4*)cmean, inter, fs);
    hipLaunchKernelGGL(topk_gather_kernel, dim3(NSAMP), dim3(256), 0, stream,
                       fs, x, out);
}